// Round 1
// 158.379 us; speedup vs baseline: 1.0673x; 1.0673x over previous
//
#include <hip/hip_runtime.h>

// filtered_lrelu: 2x FIR up (12 taps) -> lrelu(0.01) -> 2x FIR down (12 taps)
// x: [8,128,130,130] f32, filters: 12 f32, out: [8,128,128,128] f32.
//
// Gain: ref uses (2*up) per axis and unit down. We use raw up (z_ours = z_ref/4)
// and fold x2 into fd per axis (vert-down + horiz-down) => x4 total, exact
// since lrelu(s*z) = s*lrelu(z) for s>0 and downsampling is linear.
//
// v2 structure (single 22496 B LDS buffer -> 7 blocks/CU):
//   Tile 32x64 outputs/block, 256 threads, grid (4,2,1024).
//   stage A: GLOBAL -> u[74][76] horizontal up-conv directly (no xs staging,
//            no stage-0 pass; clamped-offset + cndmask boundary handling;
//            tile x footprint ~14KB lives in L1).
//   stage B: vert up + lrelu + vert down fused, sliding registers, 2 segs of
//            32 output rows; w ALIASES u: w row j of seg s stored at u slot
//            j + 10*s (seg0 -> slots 0..31, seg1 -> slots 42..73). Disjoint
//            from all cross-thread u reads; same-slot touch is a same-thread
//            read-then-write in one iteration (program order).
//   stage C: horiz down-conv, 2 rounds of 256 tasks, float4 stores.

#define TOX 32
#define TOY 64
#define UST 76          // u/w row stride (floats)
#define U_ROWS 74       // TOY + 10

__global__ __launch_bounds__(256, 7)
void flrelu_fused_kernel(const float* __restrict__ x,
                         const float* __restrict__ upf,
                         const float* __restrict__ downf,
                         float* __restrict__ out) {
    __shared__ __align__(16) float u_s[U_ROWS * UST];   // 22496 B

    const int tid = threadIdx.x;
    const int ch  = blockIdx.z;
    const int ox0 = blockIdx.x * TOX;
    const int oy0 = blockIdx.y * TOY;

    // Uniform filter loads -> SGPRs. fu raw; fd = 2*down reversed (gain split).
    float fu[12], fd[12];
#pragma unroll
    for (int t = 0; t < 12; ++t) fu[t] = upf[t];
#pragma unroll
    for (int t = 0; t < 12; ++t) fd[t] = 2.0f * downf[11 - t];

    // ---- stage A: global -> u (horizontal up-conv), rows 0..73 ----
    // task (h,g): u cols 4g..4g+3 from x row (oy0-4+h), cols (ox0-4+2g)..+6.
    // 19 g-threads x 13 h-rows per round, 6 rounds (last partial: 9 rows).
    {
        const float* __restrict__ xc = x + (size_t)ch * (130 * 130);
        const int g   = tid % 19;
        const int h0  = tid / 19;            // 0..12 for tid<247
        const int gc0 = ox0 - 4 + 2 * g;
        // hoisted column validity + clamped (always in-row-bounds) offsets
        const bool c0 = (unsigned)(gc0    ) <= 128u;
        const bool c2 = (unsigned)(gc0 + 2) <= 128u;
        const bool c4 = (unsigned)(gc0 + 4) <= 128u;
        const bool c6 = (unsigned)(gc0 + 6) <= 129u;
        const int o0 = c0 ? gc0     : 0;
        const int o2 = c2 ? gc0 + 2 : 0;
        const int o4 = c4 ? gc0 + 4 : 0;
        const int o6 = c6 ? gc0 + 6 : 0;
        if (tid < 247) {
#pragma unroll
            for (int k = 0; k < 6; ++k) {
                const int h = h0 + 13 * k;
                if (k < 5 || h < U_ROWS) {
                    const int  gr  = oy0 - 4 + h;
                    const bool rok = (unsigned)gr < 130u;
                    const int  rb  = (rok ? gr : 0) * 130;   // clamped row base
                    float2 t01 = *(const float2*)(xc + rb + o0);
                    float2 t23 = *(const float2*)(xc + rb + o2);
                    float2 t45 = *(const float2*)(xc + rb + o4);
                    float  t6  = xc[rb + o6];
                    const float s0 = c0 ? t01.x : 0.f, s1 = c0 ? t01.y : 0.f;
                    const float s2 = c2 ? t23.x : 0.f, s3 = c2 ? t23.y : 0.f;
                    const float s4 = c4 ? t45.x : 0.f, s5 = c4 ? t45.y : 0.f;
                    const float s6 = c6 ? t6    : 0.f;
                    float u0 = fu[0]*s5 + fu[2]*s4 + fu[4]*s3 + fu[6]*s2 + fu[8]*s1 + fu[10]*s0;
                    float u1 = fu[1]*s5 + fu[3]*s4 + fu[5]*s3 + fu[7]*s2 + fu[9]*s1 + fu[11]*s0;
                    float u2 = fu[0]*s6 + fu[2]*s5 + fu[4]*s4 + fu[6]*s3 + fu[8]*s2 + fu[10]*s1;
                    float u3 = fu[1]*s6 + fu[3]*s5 + fu[5]*s4 + fu[7]*s3 + fu[9]*s2 + fu[11]*s1;
                    if (!rok) { u0 = 0.f; u1 = 0.f; u2 = 0.f; u3 = 0.f; }
                    *(float4*)(u_s + h * UST + 4 * g) = make_float4(u0, u1, u2, u3);
                }
            }
        }
    }
    __syncthreads();

    // ---- stage B: vert up + lrelu + vert down, fused sliding window ----
    // 152 tasks: seg in {0,1} (32 out rows each) x 76 cols; 37 iters/task.
    // All LDS accesses at immediate offsets off fixed bases.
    // w row (m-5) of seg s written to u slot seg*42 + (m-5):
    //   seg0 -> slots 0..31 (own already-consumed rows; disjoint from seg1
    //   reads 32..73), seg1 -> slots 42..73 (the row it read this iteration;
    //   disjoint from seg0 reads 0..41). Columns are thread-private.
    if (tid < 152) {
        const int seg = (tid >= UST) ? 1 : 0;
        const int lj  = tid - seg * UST;
        const float* ucol = u_s + (seg * 32) * UST + lj;
        float*       wb   = u_s + (seg * 42) * UST + lj;
        float r0 = ucol[0*UST], r1 = ucol[1*UST], r2 = ucol[2*UST],
              r3 = ucol[3*UST], r4 = ucol[4*UST];
        float a0 = 0.f, a1 = 0.f, a2 = 0.f, a3 = 0.f, a4 = 0.f, a5 = 0.f;
#pragma unroll
        for (int m = 0; m < 5; ++m) {     // prime (no store)
            float r5 = ucol[(m + 5) * UST];
            float z0 = fu[0]*r5 + fu[2]*r4 + fu[4]*r3 + fu[6]*r2 + fu[8]*r1 + fu[10]*r0;
            float z1 = fu[1]*r5 + fu[3]*r4 + fu[5]*r3 + fu[7]*r2 + fu[9]*r1 + fu[11]*r0;
            z0 = fmaxf(z0, 0.01f * z0);
            z1 = fmaxf(z1, 0.01f * z1);
            a0 += fd[0]*z0  + fd[1]*z1;
            a1 += fd[2]*z0  + fd[3]*z1;
            a2 += fd[4]*z0  + fd[5]*z1;
            a3 += fd[6]*z0  + fd[7]*z1;
            a4 += fd[8]*z0  + fd[9]*z1;
            a5 += fd[10]*z0 + fd[11]*z1;
            a5 = a4; a4 = a3; a3 = a2; a2 = a1; a1 = a0; a0 = 0.f;
            r0 = r1; r1 = r2; r2 = r3; r3 = r4; r4 = r5;
        }
#pragma unroll
        for (int m = 5; m < 37; ++m) {    // steady (store one w row per iter)
            float r5 = ucol[(m + 5) * UST];
            float z0 = fu[0]*r5 + fu[2]*r4 + fu[4]*r3 + fu[6]*r2 + fu[8]*r1 + fu[10]*r0;
            float z1 = fu[1]*r5 + fu[3]*r4 + fu[5]*r3 + fu[7]*r2 + fu[9]*r1 + fu[11]*r0;
            z0 = fmaxf(z0, 0.01f * z0);
            z1 = fmaxf(z1, 0.01f * z1);
            a0 += fd[0]*z0  + fd[1]*z1;
            a1 += fd[2]*z0  + fd[3]*z1;
            a2 += fd[4]*z0  + fd[5]*z1;
            a3 += fd[6]*z0  + fd[7]*z1;
            a4 += fd[8]*z0  + fd[9]*z1;
            a5 += fd[10]*z0 + fd[11]*z1;
            wb[(m - 5) * UST] = a5;
            a5 = a4; a4 = a3; a3 = a2; a2 = a1; a1 = a0; a0 = 0.f;
            r0 = r1; r1 = r2; r2 = r3; r3 = r4; r4 = r5;
        }
    }
    __syncthreads();

    // ---- stage C: horizontal down-conv: w -> out 32x64 ----
    // 2 rounds x 256 tasks: oy = oyr*32 + (tid>>3), g = tid&7.
    // w row oy lives at u slot oy + 10*oyr  (= oyr*42 + (tid>>3)).
    {
        const int g = tid & 7;
        const int t = tid >> 3;
        float* __restrict__ outc = out + (size_t)ch * (128 * 128);
#pragma unroll
        for (int oyr = 0; oyr < 2; ++oyr) {
            const float* wr = u_s + (oyr * 42 + t) * UST + 8 * g;
            float4 q0 = *(const float4*)&wr[0];
            float4 q1 = *(const float4*)&wr[4];
            float4 q2 = *(const float4*)&wr[8];
            float4 q3 = *(const float4*)&wr[12];
            float2 e  = *(const float2*)&wr[16];
            float o0v = fd[0]*q0.x + fd[1]*q0.y + fd[2]*q0.z + fd[3]*q0.w
                      + fd[4]*q1.x + fd[5]*q1.y + fd[6]*q1.z + fd[7]*q1.w
                      + fd[8]*q2.x + fd[9]*q2.y + fd[10]*q2.z + fd[11]*q2.w;
            float o1v = fd[0]*q0.z + fd[1]*q0.w + fd[2]*q1.x + fd[3]*q1.y
                      + fd[4]*q1.z + fd[5]*q1.w + fd[6]*q2.x + fd[7]*q2.y
                      + fd[8]*q2.z + fd[9]*q2.w + fd[10]*q3.x + fd[11]*q3.y;
            float o2v = fd[0]*q1.x + fd[1]*q1.y + fd[2]*q1.z + fd[3]*q1.w
                      + fd[4]*q2.x + fd[5]*q2.y + fd[6]*q2.z + fd[7]*q2.w
                      + fd[8]*q3.x + fd[9]*q3.y + fd[10]*q3.z + fd[11]*q3.w;
            float o3v = fd[0]*q1.z + fd[1]*q1.w + fd[2]*q2.x + fd[3]*q2.y
                      + fd[4]*q2.z + fd[5]*q2.w + fd[6]*q3.x + fd[7]*q3.y
                      + fd[8]*q3.z + fd[9]*q3.w + fd[10]*e.x  + fd[11]*e.y;
            *(float4*)(outc + (size_t)(oy0 + oyr * 32 + t) * 128 + ox0 + 4 * g) =
                make_float4(o0v, o1v, o2v, o3v);
        }
    }
}

extern "C" void kernel_launch(void* const* d_in, const int* in_sizes, int n_in,
                              void* d_out, int out_size, void* d_ws, size_t ws_size,
                              hipStream_t stream) {
    const float* x     = (const float*)d_in[0];
    const float* upf   = (const float*)d_in[1];
    const float* downf = (const float*)d_in[2];
    float* out = (float*)d_out;

    dim3 grid(128 / TOX, 128 / TOY, 8 * 128);   // 4 x 2 x 1024
    dim3 block(256);
    flrelu_fused_kernel<<<grid, block, 0, stream>>>(x, upf, downf, out);
}

// Round 2
// 155.067 us; speedup vs baseline: 1.0901x; 1.0214x over previous
//
#include <hip/hip_runtime.h>

// filtered_lrelu: 2x FIR up (12 taps) -> lrelu(0.01) -> 2x FIR down (12 taps)
// x: [8,128,130,130] f32, filters: 12 f32, out: [8,128,128,128] f32.
//
// Gain: ref uses (2*up) per axis and unit down. We use raw up (z_ours = z_ref/4)
// and fold x2 into fd per axis (vert-down + horiz-down) => x4 total, exact
// since lrelu(s*z) = s*lrelu(z) for s>0 and downsampling is linear.
//
// v3 = v2 structure (single 22496 B LDS buffer -> 7 blocks/CU) plus:
//   - stage A: templated COLSAFE fast path (interior-x blocks skip all column
//     clamping); row clamping only in rounds 0 (top tile) / 5 (bottom tile),
//     uniform branch, folded per unrolled round.
//   - stage B: explicit depth-3 ds_read software pipeline (n0/n1/n2 chain) so
//     >=3 LDS reads stay in flight; consume lags issue by 3 iters (~180 cyc).
//     Clamped tail prefetch reads row 41 (dummy, discarded; same-thread order
//     keeps the w-alias safe).

#define TOX 32
#define TOY 64
#define UST 76          // u/w row stride (floats)
#define U_ROWS 74       // TOY + 10

template <bool COLSAFE>
__device__ __forceinline__ void stage_a(const float* __restrict__ xc,
                                        float* __restrict__ u_sh,
                                        const float* __restrict__ fu,
                                        int tid, int ox0, int oy0) {
    const int g   = tid % 19;
    const int h0  = tid / 19;            // 0..12 for tid<247
    const int gc0 = ox0 - 4 + 2 * g;
    bool c0 = true, c2 = true, c4 = true, c6 = true;
    int  o0 = gc0, o2 = gc0 + 2, o4 = gc0 + 4, o6 = gc0 + 6;
    if (!COLSAFE) {
        c0 = (unsigned)(gc0    ) <= 128u; o0 = c0 ? gc0     : 0;
        c2 = (unsigned)(gc0 + 2) <= 128u; o2 = c2 ? gc0 + 2 : 0;
        c4 = (unsigned)(gc0 + 4) <= 128u; o4 = c4 ? gc0 + 4 : 0;
        c6 = (unsigned)(gc0 + 6) <= 129u; o6 = c6 ? gc0 + 6 : 0;
    }
    if (tid < 247) {
#pragma unroll
        for (int k = 0; k < 6; ++k) {
            const int h = h0 + 13 * k;
            if (k < 5 || h < U_ROWS) {
                const int gr = oy0 - 4 + h;
                // rows OOB only possible: round 0 on the top tile, round 5 on
                // the bottom tile (k folds per unrolled copy; oy0 uniform).
                const bool mayclip = (k == 0 && oy0 == 0) || (k == 5 && oy0 != 0);
                bool rok = true;
                int  grc = gr;
                if (mayclip) { rok = (unsigned)gr < 130u; grc = rok ? gr : 0; }
                const float* __restrict__ xr = xc + grc * 130;
                float2 t01 = *(const float2*)(xr + o0);
                float2 t23 = *(const float2*)(xr + o2);
                float2 t45 = *(const float2*)(xr + o4);
                float  t6  = xr[o6];
                float s0 = t01.x, s1 = t01.y, s2 = t23.x, s3 = t23.y,
                      s4 = t45.x, s5 = t45.y, s6 = t6;
                if (!COLSAFE) {
                    s0 = c0 ? s0 : 0.f; s1 = c0 ? s1 : 0.f;
                    s2 = c2 ? s2 : 0.f; s3 = c2 ? s3 : 0.f;
                    s4 = c4 ? s4 : 0.f; s5 = c4 ? s5 : 0.f;
                    s6 = c6 ? s6 : 0.f;
                }
                float u0 = fu[0]*s5 + fu[2]*s4 + fu[4]*s3 + fu[6]*s2 + fu[8]*s1 + fu[10]*s0;
                float u1 = fu[1]*s5 + fu[3]*s4 + fu[5]*s3 + fu[7]*s2 + fu[9]*s1 + fu[11]*s0;
                float u2 = fu[0]*s6 + fu[2]*s5 + fu[4]*s4 + fu[6]*s3 + fu[8]*s2 + fu[10]*s1;
                float u3 = fu[1]*s6 + fu[3]*s5 + fu[5]*s4 + fu[7]*s3 + fu[9]*s2 + fu[11]*s1;
                if (mayclip && !rok) { u0 = 0.f; u1 = 0.f; u2 = 0.f; u3 = 0.f; }
                *(float4*)(u_sh + h * UST + 4 * g) = make_float4(u0, u1, u2, u3);
            }
        }
    }
}

__global__ __launch_bounds__(256, 7)
void flrelu_fused_kernel(const float* __restrict__ x,
                         const float* __restrict__ upf,
                         const float* __restrict__ downf,
                         float* __restrict__ out) {
    __shared__ __align__(16) float u_s[U_ROWS * UST];   // 22496 B

    const int tid = threadIdx.x;
    const int ch  = blockIdx.z;
    const int ox0 = blockIdx.x * TOX;
    const int oy0 = blockIdx.y * TOY;

    // Uniform filter loads -> SGPRs. fu raw; fd = 2*down reversed (gain split).
    float fu[12], fd[12];
#pragma unroll
    for (int t = 0; t < 12; ++t) fu[t] = upf[t];
#pragma unroll
    for (int t = 0; t < 12; ++t) fd[t] = 2.0f * downf[11 - t];

    // ---- stage A: global -> u (horizontal up-conv), rows 0..73 ----
    {
        const float* __restrict__ xc = x + (size_t)ch * (130 * 130);
        if (ox0 == 0 || ox0 + TOX == 128)
            stage_a<false>(xc, u_s, fu, tid, ox0, oy0);
        else
            stage_a<true>(xc, u_s, fu, tid, ox0, oy0);
    }
    __syncthreads();

    // ---- stage B: vert up + lrelu + vert down, fused sliding window ----
    // 152 tasks: seg in {0,1} (32 out rows each) x 76 cols; 37 iters/task.
    // w ALIASES u: w row j of seg s -> u slot j + 42*s (seg0: 0..31, seg1:
    // 42..73); all cross-seg read/write row ranges disjoint, same-seg touches
    // are same-thread (columns private) in program order.
    // Depth-3 read pipeline: iter m consumes the read issued at iter m-3.
    if (tid < 152) {
        const int seg = (tid >= UST) ? 1 : 0;
        const int lj  = tid - seg * UST;
        const float* ucol = u_s + (seg * 32) * UST + lj;
        float*       wb   = u_s + (seg * 42) * UST + lj;
        float r0 = ucol[0*UST], r1 = ucol[1*UST], r2 = ucol[2*UST],
              r3 = ucol[3*UST], r4 = ucol[4*UST];
        float n0 = ucol[5*UST], n1 = ucol[6*UST], n2 = ucol[7*UST];
        float a0 = 0.f, a1 = 0.f, a2 = 0.f, a3 = 0.f, a4 = 0.f, a5 = 0.f;
#pragma unroll
        for (int m = 0; m < 37; ++m) {
            const float r5 = n0;
            n0 = n1;
            n1 = n2;
            n2 = ucol[((m + 8 < 42) ? m + 8 : 41) * UST];  // folds per copy
            float z0 = fu[0]*r5 + fu[2]*r4 + fu[4]*r3 + fu[6]*r2 + fu[8]*r1 + fu[10]*r0;
            float z1 = fu[1]*r5 + fu[3]*r4 + fu[5]*r3 + fu[7]*r2 + fu[9]*r1 + fu[11]*r0;
            z0 = fmaxf(z0, 0.01f * z0);
            z1 = fmaxf(z1, 0.01f * z1);
            a0 += fd[0]*z0  + fd[1]*z1;
            a1 += fd[2]*z0  + fd[3]*z1;
            a2 += fd[4]*z0  + fd[5]*z1;
            a3 += fd[6]*z0  + fd[7]*z1;
            a4 += fd[8]*z0  + fd[9]*z1;
            a5 += fd[10]*z0 + fd[11]*z1;
            if (m >= 5) wb[(m - 5) * UST] = a5;
            a5 = a4; a4 = a3; a3 = a2; a2 = a1; a1 = a0; a0 = 0.f;
            r0 = r1; r1 = r2; r2 = r3; r3 = r4; r4 = r5;
        }
    }
    __syncthreads();

    // ---- stage C: horizontal down-conv: w -> out 32x64 ----
    // 2 rounds x 256 tasks: oy = oyr*32 + (tid>>3), g = tid&7.
    // w row oy lives at u slot oyr*42 + (tid>>3).
    {
        const int g = tid & 7;
        const int t = tid >> 3;
        float* __restrict__ outc = out + (size_t)ch * (128 * 128);
#pragma unroll
        for (int oyr = 0; oyr < 2; ++oyr) {
            const float* wr = u_s + (oyr * 42 + t) * UST + 8 * g;
            float4 q0 = *(const float4*)&wr[0];
            float4 q1 = *(const float4*)&wr[4];
            float4 q2 = *(const float4*)&wr[8];
            float4 q3 = *(const float4*)&wr[12];
            float2 e  = *(const float2*)&wr[16];
            float o0v = fd[0]*q0.x + fd[1]*q0.y + fd[2]*q0.z + fd[3]*q0.w
                      + fd[4]*q1.x + fd[5]*q1.y + fd[6]*q1.z + fd[7]*q1.w
                      + fd[8]*q2.x + fd[9]*q2.y + fd[10]*q2.z + fd[11]*q2.w;
            float o1v = fd[0]*q0.z + fd[1]*q0.w + fd[2]*q1.x + fd[3]*q1.y
                      + fd[4]*q1.z + fd[5]*q1.w + fd[6]*q2.x + fd[7]*q2.y
                      + fd[8]*q2.z + fd[9]*q2.w + fd[10]*q3.x + fd[11]*q3.y;
            float o2v = fd[0]*q1.x + fd[1]*q1.y + fd[2]*q1.z + fd[3]*q1.w
                      + fd[4]*q2.x + fd[5]*q2.y + fd[6]*q2.z + fd[7]*q2.w
                      + fd[8]*q3.x + fd[9]*q3.y + fd[10]*q3.z + fd[11]*q3.w;
            float o3v = fd[0]*q1.z + fd[1]*q1.w + fd[2]*q2.x + fd[3]*q2.y
                      + fd[4]*q2.z + fd[5]*q2.w + fd[6]*q3.x + fd[7]*q3.y
                      + fd[8]*q3.z + fd[9]*q3.w + fd[10]*e.x  + fd[11]*e.y;
            *(float4*)(outc + (size_t)(oy0 + oyr * 32 + t) * 128 + ox0 + 4 * g) =
                make_float4(o0v, o1v, o2v, o3v);
        }
    }
}

extern "C" void kernel_launch(void* const* d_in, const int* in_sizes, int n_in,
                              void* d_out, int out_size, void* d_ws, size_t ws_size,
                              hipStream_t stream) {
    const float* x     = (const float*)d_in[0];
    const float* upf   = (const float*)d_in[1];
    const float* downf = (const float*)d_in[2];
    float* out = (float*)d_out;

    dim3 grid(128 / TOX, 128 / TOY, 8 * 128);   // 4 x 2 x 1024
    dim3 block(256);
    flrelu_fused_kernel<<<grid, block, 0, stream>>>(x, upf, downf, out);
}

// Round 3
// 153.546 us; speedup vs baseline: 1.1009x; 1.0099x over previous
//
#include <hip/hip_runtime.h>

// filtered_lrelu: 2x FIR up (12 taps) -> lrelu(0.01) -> 2x FIR down (12 taps)
// x: [8,128,130,130] f32, filters: 12 f32, out: [8,128,128,128] f32.
//
// Gain: ref uses (2*up) per axis and unit down. We use raw up (z_ours = z_ref/4)
// and fold x2 into fd per axis (vert-down + horiz-down) => x4 total, exact
// since lrelu(s*z) = s*lrelu(z) for s>0 and downsampling is linear.
//
// v4 = v3 structure (single 22496 B LDS buffer -> 7 blocks/CU) with stage B
// FORCE-unrolled: 37 macro-expanded iterations, 6-name rotating register file
// for both the u-row window (rA..rF) and the w accumulators (wA..wF). All LDS
// offsets are compile-time immediates; no rotation movs survive SSA renaming;
// dead prime-phase FMAs are DCE-able; the compiler is free to hoist ds_reads
// as deep as the VGPR budget (72 @ 7 blocks/CU) allows.

#define TOX 32
#define TOY 64
#define UST 76          // u/w row stride (floats)
#define U_ROWS 74       // TOY + 10

template <bool COLSAFE>
__device__ __forceinline__ void stage_a(const float* __restrict__ xc,
                                        float* __restrict__ u_sh,
                                        const float* __restrict__ fu,
                                        int tid, int ox0, int oy0) {
    const int g   = tid % 19;
    const int h0  = tid / 19;            // 0..12 for tid<247
    const int gc0 = ox0 - 4 + 2 * g;
    bool c0 = true, c2 = true, c4 = true, c6 = true;
    int  o0 = gc0, o2 = gc0 + 2, o4 = gc0 + 4, o6 = gc0 + 6;
    if (!COLSAFE) {
        c0 = (unsigned)(gc0    ) <= 128u; o0 = c0 ? gc0     : 0;
        c2 = (unsigned)(gc0 + 2) <= 128u; o2 = c2 ? gc0 + 2 : 0;
        c4 = (unsigned)(gc0 + 4) <= 128u; o4 = c4 ? gc0 + 4 : 0;
        c6 = (unsigned)(gc0 + 6) <= 129u; o6 = c6 ? gc0 + 6 : 0;
    }
    if (tid < 247) {
#pragma unroll
        for (int k = 0; k < 6; ++k) {
            const int h = h0 + 13 * k;
            if (k < 5 || h < U_ROWS) {
                const int gr = oy0 - 4 + h;
                // rows OOB only possible: round 0 on the top tile, round 5 on
                // the bottom tile (k folds per unrolled copy; oy0 uniform).
                const bool mayclip = (k == 0 && oy0 == 0) || (k == 5 && oy0 != 0);
                bool rok = true;
                int  grc = gr;
                if (mayclip) { rok = (unsigned)gr < 130u; grc = rok ? gr : 0; }
                const float* __restrict__ xr = xc + grc * 130;
                float2 t01 = *(const float2*)(xr + o0);
                float2 t23 = *(const float2*)(xr + o2);
                float2 t45 = *(const float2*)(xr + o4);
                float  t6  = xr[o6];
                float s0 = t01.x, s1 = t01.y, s2 = t23.x, s3 = t23.y,
                      s4 = t45.x, s5 = t45.y, s6 = t6;
                if (!COLSAFE) {
                    s0 = c0 ? s0 : 0.f; s1 = c0 ? s1 : 0.f;
                    s2 = c2 ? s2 : 0.f; s3 = c2 ? s3 : 0.f;
                    s4 = c4 ? s4 : 0.f; s5 = c4 ? s5 : 0.f;
                    s6 = c6 ? s6 : 0.f;
                }
                float u0 = fu[0]*s5 + fu[2]*s4 + fu[4]*s3 + fu[6]*s2 + fu[8]*s1 + fu[10]*s0;
                float u1 = fu[1]*s5 + fu[3]*s4 + fu[5]*s3 + fu[7]*s2 + fu[9]*s1 + fu[11]*s0;
                float u2 = fu[0]*s6 + fu[2]*s5 + fu[4]*s4 + fu[6]*s3 + fu[8]*s2 + fu[10]*s1;
                float u3 = fu[1]*s6 + fu[3]*s5 + fu[5]*s4 + fu[7]*s3 + fu[9]*s2 + fu[11]*s1;
                if (mayclip && !rok) { u0 = 0.f; u1 = 0.f; u2 = 0.f; u3 = 0.f; }
                *(float4*)(u_sh + h * UST + 4 * g) = make_float4(u0, u1, u2, u3);
            }
        }
    }
}

__global__ __launch_bounds__(256, 7)
void flrelu_fused_kernel(const float* __restrict__ x,
                         const float* __restrict__ upf,
                         const float* __restrict__ downf,
                         float* __restrict__ out) {
    __shared__ __align__(16) float u_s[U_ROWS * UST];   // 22496 B

    const int tid = threadIdx.x;
    const int ch  = blockIdx.z;
    const int ox0 = blockIdx.x * TOX;
    const int oy0 = blockIdx.y * TOY;

    // Uniform filter loads -> SGPRs. fu raw; fd = 2*down reversed (gain split).
    float fu[12], fd[12];
#pragma unroll
    for (int t = 0; t < 12; ++t) fu[t] = upf[t];
#pragma unroll
    for (int t = 0; t < 12; ++t) fd[t] = 2.0f * downf[11 - t];

    // ---- stage A: global -> u (horizontal up-conv), rows 0..73 ----
    {
        const float* __restrict__ xc = x + (size_t)ch * (130 * 130);
        if (ox0 == 0 || ox0 + TOX == 128)
            stage_a<false>(xc, u_s, fu, tid, ox0, oy0);
        else
            stage_a<true>(xc, u_s, fu, tid, ox0, oy0);
    }
    __syncthreads();

    // ---- stage B: vert up + lrelu + vert down, fused sliding window ----
    // 152 tasks: seg in {0,1} (32 out rows each) x 76 cols; 37 steps/task,
    // FULLY macro-unrolled with compile-time LDS offsets.
    // w ALIASES u: w row j of seg s -> u slot j + 42*s (seg0: 0..31, seg1:
    // 42..73). Columns are thread-private, so every same-slot touch is a
    // same-thread same-address dependency (read row m+37 before writing it in
    // the same step for seg1) -- program order, compiler-visible, safe.
    if (tid < 152) {
        const int seg = (tid >= UST) ? 1 : 0;
        const int lj  = tid - seg * UST;
        const float* ucol = u_s + (seg * 32) * UST + lj;
        float*       wb   = u_s + (seg * 42) * UST + lj;
        float rA = ucol[0*UST], rB = ucol[1*UST], rC = ucol[2*UST],
              rD = ucol[3*UST], rE = ucol[4*UST], rF;
        float wA = 0.f, wB = 0.f, wC = 0.f, wD = 0.f, wE = 0.f, wF = 0.f;

        // STEP(m, r0..r5=rows m..m+5 (r5 loaded), w0=row m (new) .. w5=row m-5)
#define STEP(m, r0_,r1_,r2_,r3_,r4_,r5_, w0_,w1_,w2_,w3_,w4_,w5_)              \
        {                                                                      \
            r5_ = ucol[(m + 5) * UST];                                         \
            float z0 = fu[0]*r5_ + fu[2]*r4_ + fu[4]*r3_ + fu[6]*r2_           \
                     + fu[8]*r1_ + fu[10]*r0_;                                 \
            float z1 = fu[1]*r5_ + fu[3]*r4_ + fu[5]*r3_ + fu[7]*r2_           \
                     + fu[9]*r1_ + fu[11]*r0_;                                 \
            z0 = fmaxf(z0, 0.01f * z0);                                        \
            z1 = fmaxf(z1, 0.01f * z1);                                        \
            w0_  = fd[0]*z0  + fd[1]*z1;                                       \
            w1_ += fd[2]*z0  + fd[3]*z1;                                       \
            w2_ += fd[4]*z0  + fd[5]*z1;                                       \
            w3_ += fd[6]*z0  + fd[7]*z1;                                       \
            w4_ += fd[8]*z0  + fd[9]*z1;                                       \
            w5_ += fd[10]*z0 + fd[11]*z1;                                      \
            if ((m) >= 5) wb[((m) - 5) * UST] = w5_;                           \
        }
#define S6(m0)                                                                 \
        STEP(m0+0, rA,rB,rC,rD,rE,rF, wA,wF,wE,wD,wC,wB)                       \
        STEP(m0+1, rB,rC,rD,rE,rF,rA, wB,wA,wF,wE,wD,wC)                       \
        STEP(m0+2, rC,rD,rE,rF,rA,rB, wC,wB,wA,wF,wE,wD)                       \
        STEP(m0+3, rD,rE,rF,rA,rB,rC, wD,wC,wB,wA,wF,wE)                       \
        STEP(m0+4, rE,rF,rA,rB,rC,rD, wE,wD,wC,wB,wA,wF)                       \
        STEP(m0+5, rF,rA,rB,rC,rD,rE, wF,wE,wD,wC,wB,wA)

        S6(0) S6(6) S6(12) S6(18) S6(24) S6(30)
        STEP(36, rA,rB,rC,rD,rE,rF, wA,wF,wE,wD,wC,wB)
#undef S6
#undef STEP
    }
    __syncthreads();

    // ---- stage C: horizontal down-conv: w -> out 32x64 ----
    // 2 rounds x 256 tasks: oy = oyr*32 + (tid>>3), g = tid&7.
    // w row oy lives at u slot oyr*42 + (tid>>3).
    {
        const int g = tid & 7;
        const int t = tid >> 3;
        float* __restrict__ outc = out + (size_t)ch * (128 * 128);
#pragma unroll
        for (int oyr = 0; oyr < 2; ++oyr) {
            const float* wr = u_s + (oyr * 42 + t) * UST + 8 * g;
            float4 q0 = *(const float4*)&wr[0];
            float4 q1 = *(const float4*)&wr[4];
            float4 q2 = *(const float4*)&wr[8];
            float4 q3 = *(const float4*)&wr[12];
            float2 e  = *(const float2*)&wr[16];
            float o0v = fd[0]*q0.x + fd[1]*q0.y + fd[2]*q0.z + fd[3]*q0.w
                      + fd[4]*q1.x + fd[5]*q1.y + fd[6]*q1.z + fd[7]*q1.w
                      + fd[8]*q2.x + fd[9]*q2.y + fd[10]*q2.z + fd[11]*q2.w;
            float o1v = fd[0]*q0.z + fd[1]*q0.w + fd[2]*q1.x + fd[3]*q1.y
                      + fd[4]*q1.z + fd[5]*q1.w + fd[6]*q2.x + fd[7]*q2.y
                      + fd[8]*q2.z + fd[9]*q2.w + fd[10]*q3.x + fd[11]*q3.y;
            float o2v = fd[0]*q1.x + fd[1]*q1.y + fd[2]*q1.z + fd[3]*q1.w
                      + fd[4]*q2.x + fd[5]*q2.y + fd[6]*q2.z + fd[7]*q2.w
                      + fd[8]*q3.x + fd[9]*q3.y + fd[10]*q3.z + fd[11]*q3.w;
            float o3v = fd[0]*q1.z + fd[1]*q1.w + fd[2]*q2.x + fd[3]*q2.y
                      + fd[4]*q2.z + fd[5]*q2.w + fd[6]*q3.x + fd[7]*q3.y
                      + fd[8]*q3.z + fd[9]*q3.w + fd[10]*e.x  + fd[11]*e.y;
            *(float4*)(outc + (size_t)(oy0 + oyr * 32 + t) * 128 + ox0 + 4 * g) =
                make_float4(o0v, o1v, o2v, o3v);
        }
    }
}

extern "C" void kernel_launch(void* const* d_in, const int* in_sizes, int n_in,
                              void* d_out, int out_size, void* d_ws, size_t ws_size,
                              hipStream_t stream) {
    const float* x     = (const float*)d_in[0];
    const float* upf   = (const float*)d_in[1];
    const float* downf = (const float*)d_in[2];
    float* out = (float*)d_out;

    dim3 grid(128 / TOX, 128 / TOY, 8 * 128);   // 4 x 2 x 1024
    dim3 block(256);
    flrelu_fused_kernel<<<grid, block, 0, stream>>>(x, upf, downf, out);
}

// Round 4
// 149.530 us; speedup vs baseline: 1.1304x; 1.0269x over previous
//
#include <hip/hip_runtime.h>

// filtered_lrelu: 2x FIR up (12 taps) -> lrelu(0.01) -> 2x FIR down (12 taps)
// x: [8,128,130,130] f32, filters: 12 f32, out: [8,128,128,128] f32.
//
// Gain: ref uses (2*up) per axis and unit down. We fold BOTH 2x factors into
// the up filter (fu2 = 2*fu, used horizontally in stage A and vertically in
// stage B => x4 total) -- exact since lrelu(s*z)=s*lrelu(z) for s>0 and all
// later stages are linear. fd = downf reversed, RAW s_loads -> SGPRs (no
// VALU prologue, no VGPR residency).
//
// v5 = v4 (single 22496 B LDS buffer, 7 blocks/CU, stage B macro-unrolled)
// plus:
//   - all stage-B down-accumulators written as explicit nested fmaf():
//     `w += a*z0 + b*z1` under default fp-contract is mul+fma+ADD (3 instrs);
//     fmaf(a,z0,fmaf(b,z1,w)) is 2 FMAs. Saves 6 VALU instr/step in the
//     dominant loop.
//   - fd in SGPRs frees 12 VGPRs for ds_read hoisting slack.

#define TOX 32
#define TOY 64
#define UST 76          // u/w row stride (floats)
#define U_ROWS 74       // TOY + 10

template <bool COLSAFE>
__device__ __forceinline__ void stage_a(const float* __restrict__ xc,
                                        float* __restrict__ u_sh,
                                        const float* __restrict__ fu2,
                                        int tid, int ox0, int oy0) {
    const int g   = tid % 19;
    const int h0  = tid / 19;            // 0..12 for tid<247
    const int gc0 = ox0 - 4 + 2 * g;
    bool c0 = true, c2 = true, c4 = true, c6 = true;
    int  o0 = gc0, o2 = gc0 + 2, o4 = gc0 + 4, o6 = gc0 + 6;
    if (!COLSAFE) {
        c0 = (unsigned)(gc0    ) <= 128u; o0 = c0 ? gc0     : 0;
        c2 = (unsigned)(gc0 + 2) <= 128u; o2 = c2 ? gc0 + 2 : 0;
        c4 = (unsigned)(gc0 + 4) <= 128u; o4 = c4 ? gc0 + 4 : 0;
        c6 = (unsigned)(gc0 + 6) <= 129u; o6 = c6 ? gc0 + 6 : 0;
    }
    if (tid < 247) {
#pragma unroll
        for (int k = 0; k < 6; ++k) {
            const int h = h0 + 13 * k;
            if (k < 5 || h < U_ROWS) {
                const int gr = oy0 - 4 + h;
                // rows OOB only possible: round 0 on the top tile, round 5 on
                // the bottom tile (k folds per unrolled copy; oy0 uniform).
                const bool mayclip = (k == 0 && oy0 == 0) || (k == 5 && oy0 != 0);
                bool rok = true;
                int  grc = gr;
                if (mayclip) { rok = (unsigned)gr < 130u; grc = rok ? gr : 0; }
                const float* __restrict__ xr = xc + grc * 130;
                float2 t01 = *(const float2*)(xr + o0);
                float2 t23 = *(const float2*)(xr + o2);
                float2 t45 = *(const float2*)(xr + o4);
                float  t6  = xr[o6];
                float s0 = t01.x, s1 = t01.y, s2 = t23.x, s3 = t23.y,
                      s4 = t45.x, s5 = t45.y, s6 = t6;
                if (!COLSAFE) {
                    s0 = c0 ? s0 : 0.f; s1 = c0 ? s1 : 0.f;
                    s2 = c2 ? s2 : 0.f; s3 = c2 ? s3 : 0.f;
                    s4 = c4 ? s4 : 0.f; s5 = c4 ? s5 : 0.f;
                    s6 = c6 ? s6 : 0.f;
                }
                float u0 = fu2[0]*s5 + fu2[2]*s4 + fu2[4]*s3 + fu2[6]*s2 + fu2[8]*s1 + fu2[10]*s0;
                float u1 = fu2[1]*s5 + fu2[3]*s4 + fu2[5]*s3 + fu2[7]*s2 + fu2[9]*s1 + fu2[11]*s0;
                float u2 = fu2[0]*s6 + fu2[2]*s5 + fu2[4]*s4 + fu2[6]*s3 + fu2[8]*s2 + fu2[10]*s1;
                float u3 = fu2[1]*s6 + fu2[3]*s5 + fu2[5]*s4 + fu2[7]*s3 + fu2[9]*s2 + fu2[11]*s1;
                if (mayclip && !rok) { u0 = 0.f; u1 = 0.f; u2 = 0.f; u3 = 0.f; }
                *(float4*)(u_sh + h * UST + 4 * g) = make_float4(u0, u1, u2, u3);
            }
        }
    }
}

__global__ __launch_bounds__(256, 7)
void flrelu_fused_kernel(const float* __restrict__ x,
                         const float* __restrict__ upf,
                         const float* __restrict__ downf,
                         float* __restrict__ out) {
    __shared__ __align__(16) float u_s[U_ROWS * UST];   // 22496 B

    const int tid = threadIdx.x;
    const int ch  = blockIdx.z;
    const int ox0 = blockIdx.x * TOX;
    const int oy0 = blockIdx.y * TOY;

    // fu2 = 2*up (VGPR, one v_mul each); fd = down reversed (pure s_load).
    float fu2[12], fd[12];
#pragma unroll
    for (int t = 0; t < 12; ++t) fu2[t] = 2.0f * upf[t];
#pragma unroll
    for (int t = 0; t < 12; ++t) fd[t] = downf[11 - t];

    // ---- stage A: global -> u (horizontal up-conv x 2fu), rows 0..73 ----
    {
        const float* __restrict__ xc = x + (size_t)ch * (130 * 130);
        if (ox0 == 0 || ox0 + TOX == 128)
            stage_a<false>(xc, u_s, fu2, tid, ox0, oy0);
        else
            stage_a<true>(xc, u_s, fu2, tid, ox0, oy0);
    }
    __syncthreads();

    // ---- stage B: vert up (x 2fu) + lrelu + vert down, fused sliding ----
    // 152 tasks: seg in {0,1} (32 out rows each) x 76 cols; 37 steps/task,
    // FULLY macro-unrolled with compile-time LDS offsets.
    // w ALIASES u: w row j of seg s -> u slot j + 42*s (seg0: 0..31, seg1:
    // 42..73). Columns thread-private; every same-slot touch is same-thread
    // program order. Down-accumulators as nested fmaf (2 FMA per tap-pair).
    if (tid < 152) {
        const int seg = (tid >= UST) ? 1 : 0;
        const int lj  = tid - seg * UST;
        const float* ucol = u_s + (seg * 32) * UST + lj;
        float*       wb   = u_s + (seg * 42) * UST + lj;
        float rA = ucol[0*UST], rB = ucol[1*UST], rC = ucol[2*UST],
              rD = ucol[3*UST], rE = ucol[4*UST], rF;
        float wA = 0.f, wB = 0.f, wC = 0.f, wD = 0.f, wE = 0.f, wF = 0.f;

        // STEP(m, r0..r5=rows m..m+5 (r5 loaded), w0=row m (new) .. w5=row m-5)
#define STEP(m, r0_,r1_,r2_,r3_,r4_,r5_, w0_,w1_,w2_,w3_,w4_,w5_)              \
        {                                                                      \
            r5_ = ucol[(m + 5) * UST];                                         \
            float z0 = fu2[0]*r5_ + fu2[2]*r4_ + fu2[4]*r3_ + fu2[6]*r2_       \
                     + fu2[8]*r1_ + fu2[10]*r0_;                               \
            float z1 = fu2[1]*r5_ + fu2[3]*r4_ + fu2[5]*r3_ + fu2[7]*r2_       \
                     + fu2[9]*r1_ + fu2[11]*r0_;                               \
            z0 = fmaxf(z0, 0.01f * z0);                                        \
            z1 = fmaxf(z1, 0.01f * z1);                                        \
            w0_ = fmaf(fd[0], z0, fd[1] * z1);                                 \
            w1_ = fmaf(fd[2],  z0, fmaf(fd[3],  z1, w1_));                     \
            w2_ = fmaf(fd[4],  z0, fmaf(fd[5],  z1, w2_));                     \
            w3_ = fmaf(fd[6],  z0, fmaf(fd[7],  z1, w3_));                     \
            w4_ = fmaf(fd[8],  z0, fmaf(fd[9],  z1, w4_));                     \
            w5_ = fmaf(fd[10], z0, fmaf(fd[11], z1, w5_));                     \
            if ((m) >= 5) wb[((m) - 5) * UST] = w5_;                           \
        }
#define S6(m0)                                                                 \
        STEP(m0+0, rA,rB,rC,rD,rE,rF, wA,wF,wE,wD,wC,wB)                       \
        STEP(m0+1, rB,rC,rD,rE,rF,rA, wB,wA,wF,wE,wD,wC)                       \
        STEP(m0+2, rC,rD,rE,rF,rA,rB, wC,wB,wA,wF,wE,wD)                       \
        STEP(m0+3, rD,rE,rF,rA,rB,rC, wD,wC,wB,wA,wF,wE)                       \
        STEP(m0+4, rE,rF,rA,rB,rC,rD, wE,wD,wC,wB,wA,wF)                       \
        STEP(m0+5, rF,rA,rB,rC,rD,rE, wF,wE,wD,wC,wB,wA)

        S6(0) S6(6) S6(12) S6(18) S6(24) S6(30)
        STEP(36, rA,rB,rC,rD,rE,rF, wA,wF,wE,wD,wC,wB)
#undef S6
#undef STEP
    }
    __syncthreads();

    // ---- stage C: horizontal down-conv: w -> out 32x64 ----
    // 2 rounds x 256 tasks: oy = oyr*32 + (tid>>3), g = tid&7.
    // w row oy lives at u slot oyr*42 + (tid>>3).
    {
        const int g = tid & 7;
        const int t = tid >> 3;
        float* __restrict__ outc = out + (size_t)ch * (128 * 128);
#pragma unroll
        for (int oyr = 0; oyr < 2; ++oyr) {
            const float* wr = u_s + (oyr * 42 + t) * UST + 8 * g;
            float4 q0 = *(const float4*)&wr[0];
            float4 q1 = *(const float4*)&wr[4];
            float4 q2 = *(const float4*)&wr[8];
            float4 q3 = *(const float4*)&wr[12];
            float2 e  = *(const float2*)&wr[16];
            float o0v = fd[0]*q0.x + fd[1]*q0.y + fd[2]*q0.z + fd[3]*q0.w
                      + fd[4]*q1.x + fd[5]*q1.y + fd[6]*q1.z + fd[7]*q1.w
                      + fd[8]*q2.x + fd[9]*q2.y + fd[10]*q2.z + fd[11]*q2.w;
            float o1v = fd[0]*q0.z + fd[1]*q0.w + fd[2]*q1.x + fd[3]*q1.y
                      + fd[4]*q1.z + fd[5]*q1.w + fd[6]*q2.x + fd[7]*q2.y
                      + fd[8]*q2.z + fd[9]*q2.w + fd[10]*q3.x + fd[11]*q3.y;
            float o2v = fd[0]*q1.x + fd[1]*q1.y + fd[2]*q1.z + fd[3]*q1.w
                      + fd[4]*q2.x + fd[5]*q2.y + fd[6]*q2.z + fd[7]*q2.w
                      + fd[8]*q3.x + fd[9]*q3.y + fd[10]*q3.z + fd[11]*q3.w;
            float o3v = fd[0]*q1.z + fd[1]*q1.w + fd[2]*q2.x + fd[3]*q2.y
                      + fd[4]*q2.z + fd[5]*q2.w + fd[6]*q3.x + fd[7]*q3.y
                      + fd[8]*q3.z + fd[9]*q3.w + fd[10]*e.x  + fd[11]*e.y;
            *(float4*)(outc + (size_t)(oy0 + oyr * 32 + t) * 128 + ox0 + 4 * g) =
                make_float4(o0v, o1v, o2v, o3v);
        }
    }
}

extern "C" void kernel_launch(void* const* d_in, const int* in_sizes, int n_in,
                              void* d_out, int out_size, void* d_ws, size_t ws_size,
                              hipStream_t stream) {
    const float* x     = (const float*)d_in[0];
    const float* upf   = (const float*)d_in[1];
    const float* downf = (const float*)d_in[2];
    float* out = (float*)d_out;

    dim3 grid(128 / TOX, 128 / TOY, 8 * 128);   // 4 x 2 x 1024
    dim3 block(256);
    flrelu_fused_kernel<<<grid, block, 0, stream>>>(x, upf, downf, out);
}